// Round 9
// baseline (34.595 us; speedup 1.0000x reference)
//
#include <hip/hip_runtime.h>

// N=8, L=2048, E=1024, V=512. Only l=L-1 feeds logits.
// R9: leanest 3-kernel pipeline.
//  K1 role-split: blocks 0..511 pack tokens -> bits (the only 64 MB pass);
//                 blocks 512..767 compute q_row with Wa_w read exactly ONCE
//                 (all 8 last-token rows staged in LDS, wave computes 8 n).
//  K2: flash from bits (scores via masked add, chunk softmax, weighted bit-sum).
//  K3: combine + output GEMV.
#define NB 8
#define LS 2048
#define ED 1024
#define VD 512
#define CM 32           // m-rows per flash block
#define CH (LS / CM)    // 64 chunks
typedef unsigned long long u64;

__device__ inline float wave_reduce_sum(float v) {
    #pragma unroll
    for (int off = 32; off > 0; off >>= 1)
        v += __shfl_down(v, off, 64);
    return v;
}

// K1: blocks 0..511 = pack role (wave packs 8 rows; 4 waves -> 32 rows/block).
//     bit map: e = k + 4*lane + j -> word ((e>>8)<<2)|(e&3), bit (e>>2)&63.
//     blocks 512..767 = qrow role: q_row[n,f] = Wa_b[f] + xs[n] . Wa_w[f].
__global__ __launch_bounds__(256) void k_pack_qrow(const int* __restrict__ tokens,
                                                   const float* __restrict__ Wa_w,
                                                   const float* __restrict__ Wa_b,
                                                   float* __restrict__ q_row,
                                                   u64* __restrict__ pk_g) {
    __shared__ int xs[NB][ED];          // 32 KB (qrow role only)
    int b = blockIdx.x, t = threadIdx.x;
    int wave = t >> 6, lane = t & 63;
    if (b < 512) {
        #pragma unroll
        for (int i = 0; i < 8; ++i) {
            int row = b * 32 + wave * 8 + i;        // row = n*LS + m, 0..16383
            const int* xr = tokens + (size_t)row * ED;
            u64* pkr = pk_g + (size_t)row * 16;
            #pragma unroll
            for (int k = 0; k < ED; k += 256) {
                int idx = k + lane * 4;
                int4 tv = *reinterpret_cast<const int4*>(xr + idx);
                u64 b0 = __ballot(tv.x != 0);
                u64 b1 = __ballot(tv.y != 0);
                u64 b2 = __ballot(tv.z != 0);
                u64 b3 = __ballot(tv.w != 0);
                u64 bb = b0;
                bb = (lane == 1) ? b1 : bb;
                bb = (lane == 2) ? b2 : bb;
                bb = (lane == 3) ? b3 : bb;
                if (lane < 4) pkr[((k >> 8) << 2) + lane] = bb;
            }
        }
    } else {
        // stage the 8 last-token rows
        #pragma unroll
        for (int i = 0; i < 8; ++i) {
            int v4 = i * 256 + t;                   // int4 index into 8*1024 ints
            int n  = v4 >> 8;
            int e  = (v4 & 255) * 4;
            *reinterpret_cast<int4*>(&xs[n][e]) =
                *reinterpret_cast<const int4*>(&tokens[((size_t)n * LS + (LS - 1)) * ED + e]);
        }
        __syncthreads();
        int f = (b - 512) * 4 + wave;
        const float* wrow = Wa_w + (size_t)f * ED;
        float acc[NB] = {0.f, 0.f, 0.f, 0.f, 0.f, 0.f, 0.f, 0.f};
        #pragma unroll
        for (int k = 0; k < ED; k += 256) {
            int idx = k + lane * 4;
            float4 w = *reinterpret_cast<const float4*>(wrow + idx);
            #pragma unroll
            for (int n = 0; n < NB; ++n) {
                int4 tv = *reinterpret_cast<const int4*>(&xs[n][idx]);
                acc[n] += (float)tv.x * w.x + (float)tv.y * w.y
                        + (float)tv.z * w.z + (float)tv.w * w.w;
            }
        }
        #pragma unroll
        for (int n = 0; n < NB; ++n) {
            float s = wave_reduce_sum(acc[n]);
            if (lane == 0) q_row[n * ED + f] = s + Wa_b[f];
        }
    }
}

// K2: flash from bits. Block (512 thr, 8 waves) per (n, chunk of 32 m).
// q permuted so phase-1 reads are conflict-free:
//   q_perm[w*64 + bit] = q[e], w = ((e>>8)<<2)|(e&3), bit = (e>>2)&63.
__global__ __launch_bounds__(512) void k_flash(const float* __restrict__ q_row,
                                               const u64* __restrict__ pk_g,
                                               float* __restrict__ pa,
                                               float* __restrict__ mu_g,
                                               float* __restrict__ z_g) {
    int n = blockIdx.x >> 6;      // /CH
    int c = blockIdx.x & (CH - 1);
    int t = threadIdx.x;
    int wave = t >> 6, lane = t & 63;

    __shared__ u64   pk[CM * 16];   // 4 KB
    __shared__ float q_perm[ED];    // 4 KB
    __shared__ float s_lds[CM];
    __shared__ float p_lds[CM];

    pk[t] = pk_g[((size_t)(n * LS + c * CM)) * 16 + t];
    {
        float2 qq = *reinterpret_cast<const float2*>(&q_row[n * ED + t * 2]);
        int e0 = t * 2, e1 = e0 + 1;
        q_perm[((((e0 >> 8) << 2) | (e0 & 3)) << 6) | ((e0 >> 2) & 63)] = qq.x;
        q_perm[((((e1 >> 8) << 2) | (e1 & 3)) << 6) | ((e1 >> 2) & 63)] = qq.y;
    }
    __syncthreads();

    // ---- phase 1: masked-add scores (8 waves x 4 rows) ----
    #pragma unroll
    for (int i = 0; i < 4; ++i) {
        int m = wave + 8 * i;
        float acc = 0.f;
        #pragma unroll
        for (int w = 0; w < 16; ++w) {
            u64   word = pk[m * 16 + w];            // broadcast read
            float qv   = q_perm[(w << 6) | lane];   // conflict-free
            acc += ((word >> lane) & 1ull) ? qv : 0.f;
        }
        acc = wave_reduce_sum(acc);
        if (lane == 0) s_lds[m] = acc;
    }
    __syncthreads();

    // ---- phase 2: chunk softmax stats ----
    if (wave == 0) {
        float s = (lane < CM) ? s_lds[lane] : -3.0e38f;
        float mx = s;
        #pragma unroll
        for (int off = 16; off > 0; off >>= 1) mx = fmaxf(mx, __shfl_xor(mx, off, 64));
        float p = (lane < CM) ? expf(s - mx) : 0.f;
        float z = p;
        #pragma unroll
        for (int off = 16; off > 0; off >>= 1) z += __shfl_xor(z, off, 64);
        if (lane < CM) p_lds[lane] = p;
        if (lane == 0) { mu_g[blockIdx.x] = mx; z_g[blockIdx.x] = z; }
    }
    __syncthreads();

    // ---- phase 3: weighted bit-sum; thread t -> e0 = t, e1 = t + 512 ----
    int w0  = ((t >> 8) << 2) | (t & 3);
    int bit = (t >> 2) & 63;
    float a0 = 0.f, a1 = 0.f;
    #pragma unroll 8
    for (int m = 0; m < CM; ++m) {
        float p  = p_lds[m];
        u64   lo = pk[m * 16 + w0];
        u64   hi = pk[m * 16 + w0 + 8];
        a0 += ((lo >> bit) & 1ull) ? p : 0.f;
        a1 += ((hi >> bit) & 1ull) ? p : 0.f;
    }
    float* par = pa + (size_t)blockIdx.x * ED;
    par[t]       = a0;
    par[t + 512] = a1;
}

// K3: combine + GEMV. Block per (n, v-tile of 32). Wave 0 builds
// coef[c] = exp(mu_c - mu)/Z, 1024 threads combine pa into a_lds,
// then 16 waves x 2 v each dot with Wb_w.
__global__ __launch_bounds__(1024) void k_out(const float* __restrict__ pa,
                                              const float* __restrict__ mu_g,
                                              const float* __restrict__ z_g,
                                              const float* __restrict__ Wb_w,
                                              const float* __restrict__ Wb_b,
                                              float* __restrict__ out) {
    int n  = blockIdx.x >> 4;
    int vt = blockIdx.x & 15;
    int t  = threadIdx.x;
    int wave = t >> 6, lane = t & 63;
    __shared__ float coef[CH];
    __shared__ float a_lds[ED];

    if (wave == 0) {
        float m_c = mu_g[n * CH + lane];
        float mx = m_c;
        #pragma unroll
        for (int off = 32; off > 0; off >>= 1) mx = fmaxf(mx, __shfl_xor(mx, off, 64));
        float cf = expf(m_c - mx);
        float zc = z_g[n * CH + lane] * cf;
        float Z = zc;
        #pragma unroll
        for (int off = 32; off > 0; off >>= 1) Z += __shfl_xor(Z, off, 64);
        coef[lane] = cf / Z;
    }
    __syncthreads();

    float acc = 0.f;
    #pragma unroll
    for (int ci = 0; ci < CH; ++ci)
        acc += coef[ci] * pa[((size_t)(n * CH + ci)) * ED + t];
    a_lds[t] = acc;
    __syncthreads();

    #pragma unroll
    for (int i = 0; i < 2; ++i) {
        int v = vt * 32 + wave * 2 + i;
        const float* wr = Wb_w + (size_t)v * ED;
        float d = 0.f;
        #pragma unroll
        for (int k = 0; k < ED; k += 256) {
            int idx = k + lane * 4;
            float4 wv = *reinterpret_cast<const float4*>(wr + idx);
            float4 av = *reinterpret_cast<const float4*>(&a_lds[idx]);
            d += av.x * wv.x + av.y * wv.y + av.z * wv.z + av.w * wv.w;
        }
        d = wave_reduce_sum(d);
        if (lane == 0) out[n * VD + v] = d + Wb_b[v];
    }
}

extern "C" void kernel_launch(void* const* d_in, const int* in_sizes, int n_in,
                              void* d_out, int out_size, void* d_ws, size_t ws_size,
                              hipStream_t stream) {
    const int*   tokens = (const int*)  d_in[0];
    const float* Wa_w   = (const float*)d_in[1];
    const float* Wa_b   = (const float*)d_in[2];
    const float* Wb_w   = (const float*)d_in[3];
    const float* Wb_b   = (const float*)d_in[4];
    float* out = (float*)d_out;

    u64*   pk_g  = (u64*)d_ws;                           // 8*2048*16 u64 = 2 MB
    float* q_row = (float*)(pk_g + (size_t)NB * LS * 16);// 8192
    float* pa    = q_row + NB * ED;                      // 8*64*1024 = 524288
    float* mu_g  = pa + (size_t)NB * CH * ED;            // 512
    float* z_g   = mu_g + NB * CH;                       // 512

    // 1) pack (blocks 0..511) + qrow (blocks 512..767): the only 64 MB pass,
    //    Wa_w read exactly once.
    k_pack_qrow<<<dim3(768), dim3(256), 0, stream>>>(tokens, Wa_w, Wa_b, q_row, pk_g);
    // 2) flash from packed bits: 512 blocks of 512 (2 MB, L2-hot)
    k_flash<<<dim3(NB * CH), dim3(512), 0, stream>>>(q_row, pk_g, pa, mu_g, z_g);
    // 3) combine + output GEMV: 128 blocks of 1024
    k_out<<<dim3(NB * 16), dim3(1024), 0, stream>>>(pa, mu_g, z_g, Wb_w, Wb_b, out);
}